// Round 1
// 617.849 us; speedup vs baseline: 1.1635x; 1.1635x over previous
//
#include <hip/hip_runtime.h>

// FMLayer: out[b, p] = <w[j1], w[j2]> * x[b, j1] * x[b, j2] for triu pairs (j1<j2)
// N=512, K=4, B=1024, P=130816. Inputs fp32, output fp32.
//
// R3 redesign: one block per batch row, fully-sequential 523 KB write stream per
// block (fixes write fragmentation: prior layout = 32K interleaved ~1KB segments
// -> ~1.5 TB/s effective; fill kernel proves 6.1 TB/s with contiguous streams).
// wdot[p] precomputed into d_ws; main kernel double-buffers 16 KB wdot chunks
// through LDS with issue-early/write-late staging so the store stream is not
// vmcnt-coupled to loads. j1(p) via closed-form sqrt + fixup. All LDS reads
// stride-1 or broadcast.

#define NF      512
#define KDIM    4
#define BATCH   1024
#define NPAIRS  130816   // 512*511/2
#define WDPAD   131072   // NPAIRS padded to CHUNK multiple (+256 zeros)
#define CHUNK   4096     // wdot floats per LDS chunk (16 KB)
#define NCHUNK  32       // ceil(NPAIRS / CHUNK); last chunk = 3840
#define TPB     256
#define BT      16       // fallback path only

__device__ __forceinline__ int rowoff(int j) {
    // start offset of row j1=j in flattened triu pair space
    return (j * (1023 - j)) >> 1;
}

// ---------- kernel 1: wdot table (523 KB) + zero pad ----------
__global__ __launch_bounds__(TPB) void fm_wdot(
    const float* __restrict__ w,     // [NF, KDIM]
    float* __restrict__ wd)          // [WDPAD]
{
    const int j1 = blockIdx.x;
    if (j1 == NF - 1) {              // pad block: zero [NPAIRS, WDPAD) = 256 entries
        wd[NPAIRS + threadIdx.x] = 0.f;
        return;
    }
    const int L   = (NF - 1) - j1;
    const int off = rowoff(j1);
    const float wa0 = w[j1*KDIM+0], wa1 = w[j1*KDIM+1],
                wa2 = w[j1*KDIM+2], wa3 = w[j1*KDIM+3];
    for (int t = threadIdx.x; t < L; t += TPB) {
        const int j2 = j1 + 1 + t;
        wd[off + t] = wa0*w[j2*KDIM+0] + wa1*w[j2*KDIM+1]
                    + wa2*w[j2*KDIM+2] + wa3*w[j2*KDIM+3];
    }
}

// ---------- kernel 2: main stream, one block per batch row ----------
__global__ __launch_bounds__(TPB) void fm_main(
    const float* __restrict__ x,     // [BATCH, NF]
    const float* __restrict__ wd,    // [WDPAD]
    float* __restrict__ out)         // [BATCH, NPAIRS]
{
    __shared__ float xs[NF];              // 2 KB
    __shared__ float wbuf[2][CHUNK];      // 32 KB double buffer

    const int b = blockIdx.x;
    const int t = threadIdx.x;

    // prologue: stage x row + chunk 0
    {
        if (t < NF/4)
            reinterpret_cast<float4*>(xs)[t] =
                reinterpret_cast<const float4*>(x + (size_t)b * NF)[t];
        const float4* s0 = reinterpret_cast<const float4*>(wd);
        float4* d0 = reinterpret_cast<float4*>(wbuf[0]);
#pragma unroll
        for (int i = 0; i < 4; ++i) d0[t + TPB*i] = s0[t + TPB*i];
    }
    __syncthreads();

    float* const obase = out + (size_t)b * NPAIRS;

    for (int c = 0; c < NCHUNK; ++c) {
        // issue next chunk's global loads EARLY (regs); LDS-write them LATE,
        // so HBM latency hides under this chunk's compute+stores.
        float4 st0, st1, st2, st3;
        if (c + 1 < NCHUNK) {
            const float4* s = reinterpret_cast<const float4*>(wd + (c + 1) * CHUNK);
            st0 = s[t];          st1 = s[t + TPB];
            st2 = s[t + 2*TPB];  st3 = s[t + 3*TPB];
        }

        const float* wb = wbuf[c & 1];
        const int p0 = c * CHUNK;
        const int klim = (NPAIRS - p0 >= CHUNK) ? (CHUNK / TPB)
                                                : ((NPAIRS - p0) / TPB); // 16 or 15
        for (int k = 0; k < klim; ++k) {
            const int pl = (k << 8) + t;
            const int p  = p0 + pl;
            // j1 = floor((1023 - sqrt(1023^2 - 8p)) / 2), then exact fixup
            const float s = sqrtf((float)(1046529 - 8 * p));
            int j1 = (int)((1023.0f - s) * 0.5f);
            j1 = j1 < 0 ? 0 : (j1 > 510 ? 510 : j1);
            while (rowoff(j1 + 1) <= p) ++j1;   // rowoff(511)=NPAIRS stops it
            while (rowoff(j1) > p) --j1;
            const int j2 = p - rowoff(j1) + j1 + 1;
            // xs[j1]: wave-broadcast; xs[j2], wb[pl]: stride-1 -> conflict-free
            obase[p] = wb[pl] * xs[j1] * xs[j2];
        }

        if (c + 1 < NCHUNK) {   // late LDS write (vmcnt wait lands here, once/16KB)
            float4* d = reinterpret_cast<float4*>(wbuf[(c + 1) & 1]);
            d[t] = st0; d[t + TPB] = st1; d[t + 2*TPB] = st2; d[t + 3*TPB] = st3;
        }
        __syncthreads();
    }
}

// ---------- fallback (previous kernel) if workspace is too small ----------
__global__ __launch_bounds__(TPB) void fm_kernel(
    const float* __restrict__ x,
    const float* __restrict__ w,
    float* __restrict__ out)
{
    const int j1  = blockIdx.x;
    const int b0  = blockIdx.y * BT;
    const int L   = (NF - 1) - j1;
    const int off = j1 * (NF - 1) - (j1 * (j1 - 1)) / 2;

    const float wa0 = w[j1 * KDIM + 0];
    const float wa1 = w[j1 * KDIM + 1];
    const float wa2 = w[j1 * KDIM + 2];
    const float wa3 = w[j1 * KDIM + 3];

    __shared__ float wdl[NF - 1];
    for (int t = threadIdx.x; t < L; t += TPB) {
        const int j2 = j1 + 1 + t;
        wdl[t] = wa0 * w[j2 * KDIM + 0] + wa1 * w[j2 * KDIM + 1]
               + wa2 * w[j2 * KDIM + 2] + wa3 * w[j2 * KDIM + 3];
    }
    __syncthreads();

    for (int bi = 0; bi < BT; ++bi) {
        const int b = b0 + bi;
        const float xj1 = x[(size_t)b * NF + j1];
        const float* __restrict__ xrow = x + (size_t)b * NF + (j1 + 1);
        float* __restrict__ orow = out + (size_t)b * NPAIRS + off;
        for (int t = threadIdx.x; t < L; t += TPB) {
            orow[t] = wdl[t] * xj1 * xrow[t];
        }
    }
}

extern "C" void kernel_launch(void* const* d_in, const int* in_sizes, int n_in,
                              void* d_out, int out_size, void* d_ws, size_t ws_size,
                              hipStream_t stream) {
    const float* x = (const float*)d_in[0];     // [1024, 512] fp32
    const float* w = (const float*)d_in[1];     // [512, 4]   fp32
    float* out = (float*)d_out;                 // [1024, 130816] fp32

    if (ws_size >= (size_t)WDPAD * sizeof(float)) {
        float* wd = (float*)d_ws;
        fm_wdot<<<dim3(NF), TPB, 0, stream>>>(w, wd);          // 512 blocks
        fm_main<<<dim3(BATCH), TPB, 0, stream>>>(x, wd, out);  // 1024 blocks, 4/CU
    } else {
        dim3 grid(NF - 1, BATCH / BT);
        fm_kernel<<<grid, TPB, 0, stream>>>(x, w, out);
    }
}

// Round 3
// 532.857 us; speedup vs baseline: 1.3491x; 1.1595x over previous
//
#include <hip/hip_runtime.h>

// FMLayer: out[b, p] = <w[j1], w[j2]> * x[b, j1] * x[b, j2] for triu pairs (j1<j2)
// N=512, K=4, B=1024, P=130816. Inputs fp32, output fp32.
//
// R5 = R4 with the compile fix: __builtin_nontemporal_store requires a native
// clang vector type, not HIP_vector_type float4 -> use ext_vector_type(4).
//
// Design (unchanged):
//  - wd[p] table precomputed in d_ws (523 KB, L2-resident; read stride-1 by all
//    blocks directly from global -- no LDS staging, no per-chunk __syncthreads,
//    so the store stream is never drained by a barrier's vmcnt(0)).
//  - f32x4 wd loads + f32x4 NON-TEMPORAL output stores (output never re-read;
//    keeps L2 for the wd table). One sqrt per 4 pairs, incremental row-walk.
//  - grid = (1024 rows) x (2 half-rows) = 2048 blocks = 8/CU x 4 waves = 32
//    waves/CU full occupancy; each block writes one 262 KB contiguous stream.
//  - NPAIRS % 4 == 0 and groups 4-aligned => pad boundary never splits a
//    f32x4 group; tail is a pure lane skip.

#define NF      512
#define KDIM    4
#define BATCH   1024
#define NPAIRS  130816   // 512*511/2
#define WDPAD   131072   // NPAIRS padded (+256 zero entries)
#define TPB     256
#define SPLIT   2
#define PBLK    (WDPAD / SPLIT)        // 65536 pair-slots per block
#define NIT     (PBLK / (TPB * 4))     // 64 iterations of 1024 pairs
#define BT      16                     // fallback path only

typedef float f32x4 __attribute__((ext_vector_type(4)));

__device__ __forceinline__ int rowoff(int j) {
    return (j * (1023 - j)) >> 1;      // start offset of row j1=j
}

// ---------- kernel 1: wdot table (523 KB) + zero pad ----------
__global__ __launch_bounds__(TPB) void fm_wdot(
    const float* __restrict__ w,     // [NF, KDIM]
    float* __restrict__ wd)          // [WDPAD]
{
    const int j1 = blockIdx.x;
    if (j1 == NF - 1) {              // pad block: zero [NPAIRS, WDPAD)
        wd[NPAIRS + threadIdx.x] = 0.f;
        return;
    }
    const int L   = (NF - 1) - j1;
    const int off = rowoff(j1);
    const float wa0 = w[j1*KDIM+0], wa1 = w[j1*KDIM+1],
                wa2 = w[j1*KDIM+2], wa3 = w[j1*KDIM+3];
    for (int t = threadIdx.x; t < L; t += TPB) {
        const int j2 = j1 + 1 + t;
        wd[off + t] = wa0*w[j2*KDIM+0] + wa1*w[j2*KDIM+1]
                    + wa2*w[j2*KDIM+2] + wa3*w[j2*KDIM+3];
    }
}

// ---------- kernel 2: barrier-free streaming main ----------
__global__ __launch_bounds__(TPB) void fm_main2(
    const float* __restrict__ x,     // [BATCH, NF]
    const float* __restrict__ wd,    // [WDPAD]
    float* __restrict__ out)         // [BATCH, NPAIRS]
{
    __shared__ float xs[NF];         // 2 KB; only LDS use

    const int b = blockIdx.x;
    const int t = threadIdx.x;

    if (t < NF / 4)
        reinterpret_cast<f32x4*>(xs)[t] =
            reinterpret_cast<const f32x4*>(x + (size_t)b * NF)[t];
    __syncthreads();                 // the only barrier in this kernel

    const int pbase = blockIdx.y * PBLK;
    float* const obase = out + (size_t)b * NPAIRS;

    // prefetch rotation: wd load for iter i+1 is issued BEFORE iter i's store,
    // so the load-use wait never drains outstanding stores.
    f32x4 wv = *reinterpret_cast<const f32x4*>(wd + pbase + (t << 2));

    for (int it = 0; it < NIT; ++it) {
        const int p = pbase + it * (TPB * 4) + (t << 2);

        f32x4 nwv = (f32x4){0.f, 0.f, 0.f, 0.f};
        if (it + 1 < NIT)
            nwv = *reinterpret_cast<const f32x4*>(wd + p + TPB * 4);

        if (p < NPAIRS) {            // group fully valid (NPAIRS % 4 == 0)
            // j1 estimate: floor((1023 - sqrt(1023^2 - 8p)) / 2), then walk.
            const float s = sqrtf((float)(1046529 - 8 * p));
            int j1 = (int)((1023.0f - s) * 0.5f);
            j1 = j1 < 0 ? 0 : (j1 > 510 ? 510 : j1);
            int len = 511 - j1;
            int r   = (j1 * (1023 - j1)) >> 1;     // rowoff(j1)
            while (r > p)        { --j1; ++len; r -= len; }
            while (p >= r + len) { r += len; --len; ++j1; }

            float xj1 = xs[j1];
            f32x4 o;
            o.x = wv.x * xj1 * xs[p     - r + j1 + 1];
            if (p + 1 >= r + len) { r += len; --len; ++j1; xj1 = xs[j1]; }
            o.y = wv.y * xj1 * xs[p + 1 - r + j1 + 1];
            if (p + 2 >= r + len) { r += len; --len; ++j1; xj1 = xs[j1]; }
            o.z = wv.z * xj1 * xs[p + 2 - r + j1 + 1];
            if (p + 3 >= r + len) { r += len; --len; ++j1; xj1 = xs[j1]; }
            o.w = wv.w * xj1 * xs[p + 3 - r + j1 + 1];

            __builtin_nontemporal_store(o, reinterpret_cast<f32x4*>(obase + p));
        }
        wv = nwv;
    }
}

// ---------- fallback (round-2 kernel) if workspace is too small ----------
__global__ __launch_bounds__(TPB) void fm_kernel(
    const float* __restrict__ x,
    const float* __restrict__ w,
    float* __restrict__ out)
{
    const int j1  = blockIdx.x;
    const int b0  = blockIdx.y * BT;
    const int L   = (NF - 1) - j1;
    const int off = j1 * (NF - 1) - (j1 * (j1 - 1)) / 2;

    const float wa0 = w[j1 * KDIM + 0];
    const float wa1 = w[j1 * KDIM + 1];
    const float wa2 = w[j1 * KDIM + 2];
    const float wa3 = w[j1 * KDIM + 3];

    __shared__ float wdl[NF - 1];
    for (int t = threadIdx.x; t < L; t += TPB) {
        const int j2 = j1 + 1 + t;
        wdl[t] = wa0 * w[j2 * KDIM + 0] + wa1 * w[j2 * KDIM + 1]
               + wa2 * w[j2 * KDIM + 2] + wa3 * w[j2 * KDIM + 3];
    }
    __syncthreads();

    for (int bi = 0; bi < BT; ++bi) {
        const int b = b0 + bi;
        const float xj1 = x[(size_t)b * NF + j1];
        const float* __restrict__ xrow = x + (size_t)b * NF + (j1 + 1);
        float* __restrict__ orow = out + (size_t)b * NPAIRS + off;
        for (int t = threadIdx.x; t < L; t += TPB) {
            orow[t] = wdl[t] * xj1 * xrow[t];
        }
    }
}

extern "C" void kernel_launch(void* const* d_in, const int* in_sizes, int n_in,
                              void* d_out, int out_size, void* d_ws, size_t ws_size,
                              hipStream_t stream) {
    const float* x = (const float*)d_in[0];     // [1024, 512] fp32
    const float* w = (const float*)d_in[1];     // [512, 4]   fp32
    float* out = (float*)d_out;                 // [1024, 130816] fp32

    if (ws_size >= (size_t)WDPAD * sizeof(float)) {
        float* wd = (float*)d_ws;
        fm_wdot<<<dim3(NF), TPB, 0, stream>>>(w, wd);            // 512 blocks
        fm_main2<<<dim3(BATCH, SPLIT), TPB, 0, stream>>>(x, wd, out); // 2048 blocks
    } else {
        dim3 grid(NF - 1, BATCH / BT);
        fm_kernel<<<grid, TPB, 0, stream>>>(x, w, out);
    }
}